// Round 2
// baseline (1271.956 us; speedup 1.0000x reference)
//
#include <hip/hip_runtime.h>

#define D_MODEL 512
#define N_HEADS 8
#define D_HEAD  64
#define SEQ     2048
#define BATCH   4
#define ROWS    (BATCH * SEQ)   /* 8192 */
#define EPS     1e-5f
#define SCALE   0.125f          /* 1/sqrt(64) */

// ---------------------------------------------------------------------------
// Kernel 1: LayerNorm.  One block (128 threads) per row of 512 floats.
// Each thread owns one float4; two-wave block reduce via shfl + LDS.
// ---------------------------------------------------------------------------
__global__ __launch_bounds__(128) void ln_kernel(const float* __restrict__ x,
                                                 const float* __restrict__ gamma,
                                                 const float* __restrict__ beta,
                                                 float* __restrict__ xn) {
  const int row = blockIdx.x;
  const int t   = threadIdx.x;
  const float4 v = ((const float4*)(x + (size_t)row * D_MODEL))[t];
  float s  = v.x + v.y + v.z + v.w;
  float s2 = v.x*v.x + v.y*v.y + v.z*v.z + v.w*v.w;
#pragma unroll
  for (int o = 32; o > 0; o >>= 1) {
    s  += __shfl_down(s,  o, 64);
    s2 += __shfl_down(s2, o, 64);
  }
  __shared__ float ps[2], ps2[2];
  if ((t & 63) == 0) { ps[t >> 6] = s; ps2[t >> 6] = s2; }
  __syncthreads();
  s  = ps[0] + ps[1];
  s2 = ps2[0] + ps2[1];
  const float mu  = s * (1.0f / D_MODEL);
  const float var = s2 * (1.0f / D_MODEL) - mu * mu;
  const float rs  = rsqrtf(var + EPS);
  const float4 g = ((const float4*)gamma)[t];
  const float4 b = ((const float4*)beta)[t];
  float4 o;
  o.x = (v.x - mu) * rs * g.x + b.x;
  o.y = (v.y - mu) * rs * g.y + b.y;
  o.z = (v.z - mu) * rs * g.z + b.z;
  o.w = (v.w - mu) * rs * g.w + b.w;
  ((float4*)(xn + (size_t)row * D_MODEL))[t] = o;
}

// ---------------------------------------------------------------------------
// Shared fp32 GEMM mainloop: C_tile(64x64) += A(64x512) * W(512x64)
// 256 threads as 16x16, each computes a 4x4 micro-tile. BK=16.
// As is stored k-major [16][68] (pad 68 keeps float4 reads 16B-aligned and
// spreads the transpose-write across banks). Bs[16][64]: reads are 2-way
// aliased (free) / broadcast.
// ---------------------------------------------------------------------------
__device__ __forceinline__ void gemm_mainloop(const float* __restrict__ A,
                                              const float* __restrict__ W,
                                              float (&As)[16][68],
                                              float (&Bs)[16][64],
                                              float (&c)[4][4],
                                              int bm, int bn, int tx, int ty, int tid) {
  const int lr  = tid >> 2,  lk4 = (tid & 3) * 4;   // A tile: row, k-offset
  const int blr = tid >> 4,  bln = (tid & 15) * 4;  // B tile: k-row, n-offset
  for (int bk = 0; bk < D_MODEL / 16; bk++) {
    const float4 a4 = *(const float4*)(A + (size_t)(bm * 64 + lr) * D_MODEL + bk * 16 + lk4);
    const float4 b4 = *(const float4*)(W + (size_t)(bk * 16 + blr) * D_MODEL + bn * 64 + bln);
    __syncthreads();  // previous tile fully consumed
    As[lk4 + 0][lr] = a4.x;
    As[lk4 + 1][lr] = a4.y;
    As[lk4 + 2][lr] = a4.z;
    As[lk4 + 3][lr] = a4.w;
    *(float4*)&Bs[blr][bln] = b4;
    __syncthreads();
#pragma unroll
    for (int kk = 0; kk < 16; kk++) {
      const float4 a = *(const float4*)&As[kk][ty * 4];
      const float4 b = *(const float4*)&Bs[kk][tx * 4];
      c[0][0] += a.x * b.x; c[0][1] += a.x * b.y; c[0][2] += a.x * b.z; c[0][3] += a.x * b.w;
      c[1][0] += a.y * b.x; c[1][1] += a.y * b.y; c[1][2] += a.y * b.z; c[1][3] += a.y * b.w;
      c[2][0] += a.z * b.x; c[2][1] += a.z * b.y; c[2][2] += a.z * b.z; c[2][3] += a.z * b.w;
      c[3][0] += a.w * b.x; c[3][1] += a.w * b.y; c[3][2] += a.w * b.z; c[3][3] += a.w * b.w;
    }
  }
}

// ---------------------------------------------------------------------------
// Kernel 2: QKV projection. grid = (ROWS/64, N_HEADS, 3).
// BN=64 == D_HEAD, so blockIdx.y IS the head index; output written directly
// in [B][H][S][64] layout (the reference's post-transpose layout).
// ---------------------------------------------------------------------------
__global__ __launch_bounds__(256) void qkv_kernel(const float* __restrict__ xn,
                                                  const float* __restrict__ wq, const float* __restrict__ bq,
                                                  const float* __restrict__ wk, const float* __restrict__ bk,
                                                  const float* __restrict__ wv, const float* __restrict__ bv,
                                                  float* __restrict__ qo, float* __restrict__ ko,
                                                  float* __restrict__ vo) {
  __shared__ float As[16][68];
  __shared__ float Bs[16][64];
  const float* w; const float* bias; float* out;
  switch (blockIdx.z) {
    case 0:  w = wq; bias = bq; out = qo; break;
    case 1:  w = wk; bias = bk; out = ko; break;
    default: w = wv; bias = bv; out = vo; break;
  }
  const int tid = threadIdx.x, tx = tid & 15, ty = tid >> 4;
  float c[4][4] = {};
  gemm_mainloop(xn, w, As, Bs, c, blockIdx.x, blockIdx.y, tx, ty, tid);
  const float4 bias4 = *(const float4*)(bias + blockIdx.y * 64 + tx * 4);
#pragma unroll
  for (int i = 0; i < 4; i++) {
    const int r  = blockIdx.x * 64 + ty * 4 + i;
    const int b_ = r >> 11;            // r / SEQ
    const int s  = r & (SEQ - 1);      // r % SEQ
    float4 cv;
    cv.x = c[i][0] + bias4.x; cv.y = c[i][1] + bias4.y;
    cv.z = c[i][2] + bias4.z; cv.w = c[i][3] + bias4.w;
    *(float4*)(out + ((size_t)(b_ * N_HEADS + blockIdx.y) * SEQ + s) * D_HEAD + tx * 4) = cv;
  }
}

// ---------------------------------------------------------------------------
// Kernel 3: flash attention, fp32, online softmax, no SxS materialization.
// grid = (SEQ/128, BATCH*N_HEADS), 256 threads.
// 2 threads per q-row (each owns 32 of the 64 dims); K/V tiles of 16 rows
// staged in LDS; score = partial dot + one shfl_xor(1).
// ---------------------------------------------------------------------------
#define KT 16
__global__ __launch_bounds__(256) void attn_kernel(const float* __restrict__ q,
                                                   const float* __restrict__ k,
                                                   const float* __restrict__ v,
                                                   float* __restrict__ att) {
  __shared__ float Ks[KT][64];
  __shared__ float Vs[KT][64];
  const int bh   = blockIdx.y;
  const int row  = blockIdx.x * 128 + (threadIdx.x >> 1);
  const int doff = (threadIdx.x & 1) * 32;

  // load my half of the q row, pre-scaled by 1/sqrt(d)
  float qr[32];
  const float* qp = q + ((size_t)bh * SEQ + row) * D_HEAD + doff;
#pragma unroll
  for (int j = 0; j < 8; j++) {
    const float4 t = ((const float4*)qp)[j];
    qr[4*j+0] = t.x * SCALE; qr[4*j+1] = t.y * SCALE;
    qr[4*j+2] = t.z * SCALE; qr[4*j+3] = t.w * SCALE;
  }

  float m = -1e30f, l = 0.0f;
  float o[32];
#pragma unroll
  for (int j = 0; j < 32; j++) o[j] = 0.0f;

  const float* kbase = k + (size_t)bh * SEQ * D_HEAD;
  const float* vbase = v + (size_t)bh * SEQ * D_HEAD;

  for (int kt = 0; kt < SEQ / KT; kt++) {
    {  // stage K/V tile: one float4 of K and one of V per thread
      const int lr = threadIdx.x >> 4, c4 = (threadIdx.x & 15) * 4;
      *(float4*)&Ks[lr][c4] = *(const float4*)(kbase + (size_t)(kt * KT + lr) * D_HEAD + c4);
      *(float4*)&Vs[lr][c4] = *(const float4*)(vbase + (size_t)(kt * KT + lr) * D_HEAD + c4);
    }
    __syncthreads();

    float sc[KT];
#pragma unroll
    for (int kk = 0; kk < KT; kk++) {
      const float4* kr = (const float4*)&Ks[kk][doff];
      float d0 = 0.f, d1 = 0.f, d2 = 0.f, d3 = 0.f;
#pragma unroll
      for (int j = 0; j < 8; j++) {
        const float4 kv = kr[j];
        d0 += qr[4*j+0] * kv.x; d1 += qr[4*j+1] * kv.y;
        d2 += qr[4*j+2] * kv.z; d3 += qr[4*j+3] * kv.w;
      }
      const float d = (d0 + d1) + (d2 + d3);
      sc[kk] = d + __shfl_xor(d, 1, 64);  // combine the two halves of the row
    }

    float mt = sc[0];
#pragma unroll
    for (int kk = 1; kk < KT; kk++) mt = fmaxf(mt, sc[kk]);
    const float mn   = fmaxf(m, mt);
    const float corr = __expf(m - mn);
    l *= corr;
#pragma unroll
    for (int j = 0; j < 32; j++) o[j] *= corr;

#pragma unroll
    for (int kk = 0; kk < KT; kk++) {
      const float p = __expf(sc[kk] - mn);
      l += p;
      const float4* vr = (const float4*)&Vs[kk][doff];
#pragma unroll
      for (int j = 0; j < 8; j++) {
        const float4 vv = vr[j];
        o[4*j+0] += p * vv.x; o[4*j+1] += p * vv.y;
        o[4*j+2] += p * vv.z; o[4*j+3] += p * vv.w;
      }
    }
    m = mn;
    __syncthreads();
  }

  const float rinv = 1.0f / l;
  const int b_ = bh >> 3, h = bh & 7;
  float* op = att + ((size_t)(b_ * SEQ + row)) * D_MODEL + h * D_HEAD + doff;
#pragma unroll
  for (int j = 0; j < 8; j++) {
    float4 t;
    t.x = o[4*j+0] * rinv; t.y = o[4*j+1] * rinv;
    t.z = o[4*j+2] * rinv; t.w = o[4*j+3] * rinv;
    ((float4*)op)[j] = t;
  }
}

// ---------------------------------------------------------------------------
// Kernel 4: output projection + bias + residual. grid = (ROWS/64, 8).
// ---------------------------------------------------------------------------
__global__ __launch_bounds__(256) void proj_kernel(const float* __restrict__ att,
                                                   const float* __restrict__ wo,
                                                   const float* __restrict__ bo,
                                                   const float* __restrict__ x,
                                                   float* __restrict__ out) {
  __shared__ float As[16][68];
  __shared__ float Bs[16][64];
  const int tid = threadIdx.x, tx = tid & 15, ty = tid >> 4;
  float c[4][4] = {};
  gemm_mainloop(att, wo, As, Bs, c, blockIdx.x, blockIdx.y, tx, ty, tid);
  const float4 bias4 = *(const float4*)(bo + blockIdx.y * 64 + tx * 4);
#pragma unroll
  for (int i = 0; i < 4; i++) {
    const int r = blockIdx.x * 64 + ty * 4 + i;
    const size_t off = (size_t)r * D_MODEL + blockIdx.y * 64 + tx * 4;
    const float4 xr = *(const float4*)(x + off);
    float4 cv;
    cv.x = c[i][0] + bias4.x + xr.x; cv.y = c[i][1] + bias4.y + xr.y;
    cv.z = c[i][2] + bias4.z + xr.z; cv.w = c[i][3] + bias4.w + xr.w;
    *(float4*)(out + off) = cv;
  }
}

// ---------------------------------------------------------------------------
extern "C" void kernel_launch(void* const* d_in, const int* in_sizes, int n_in,
                              void* d_out, int out_size, void* d_ws, size_t ws_size,
                              hipStream_t stream) {
  const float* x     = (const float*)d_in[0];
  const float* wq    = (const float*)d_in[1];
  const float* bq    = (const float*)d_in[2];
  const float* wk    = (const float*)d_in[3];
  const float* bk    = (const float*)d_in[4];
  const float* wv    = (const float*)d_in[5];
  const float* bv    = (const float*)d_in[6];
  const float* wo    = (const float*)d_in[7];
  const float* bo    = (const float*)d_in[8];
  const float* gamma = (const float*)d_in[9];
  const float* beta  = (const float*)d_in[10];
  float* out = (float*)d_out;

  // workspace: xn | q | k | v   (4 x 16 MiB = 64 MiB); att reuses xn's slot
  float* xn  = (float*)d_ws;
  float* q   = xn + (size_t)ROWS * D_MODEL;
  float* k   = q  + (size_t)ROWS * D_MODEL;
  float* v   = k  + (size_t)ROWS * D_MODEL;
  float* att = xn;  // xn dead after qkv_kernel

  ln_kernel<<<ROWS, 128, 0, stream>>>(x, gamma, beta, xn);
  qkv_kernel<<<dim3(ROWS / 64, N_HEADS, 3), 256, 0, stream>>>(
      xn, wq, bq, wk, bk, wv, bv, q, k, v);
  attn_kernel<<<dim3(SEQ / 128, BATCH * N_HEADS), 256, 0, stream>>>(q, k, v, att);
  proj_kernel<<<dim3(ROWS / 64, D_MODEL / 64), 256, 0, stream>>>(att, wo, bo, x, out);
}

// Round 7
// 348.111 us; speedup vs baseline: 3.6539x; 3.6539x over previous
//
#include <hip/hip_runtime.h>
#include <hip/hip_bf16.h>

#define D_MODEL 512
#define N_HEADS 8
#define D_HEAD  64
#define SEQ     2048
#define BATCH   4
#define ROWS    (BATCH * SEQ)   /* 8192 */
#define EPS     1e-5f
#define SCALE   0.125f          /* 1/sqrt(64), exact pow2 -> folded into q epilogue */

typedef __attribute__((ext_vector_type(8))) short short8;   // 8 bf16 (4 VGPRs)
typedef __attribute__((ext_vector_type(4))) float f32x4;    // MFMA C/D

__device__ __forceinline__ unsigned short f2bf(float f) {
  return __builtin_bit_cast(unsigned short, __float2bfloat16(f));  // RNE
}

// ---------------------------------------------------------------------------
// Kernel 1: LayerNorm. fp32 math (known-good), bf16 output.
// ---------------------------------------------------------------------------
__global__ __launch_bounds__(128) void ln_kernel(const float* __restrict__ x,
                                                 const float* __restrict__ gamma,
                                                 const float* __restrict__ beta,
                                                 unsigned short* __restrict__ xn) {
  const int row = blockIdx.x;
  const int t   = threadIdx.x;
  const float4 v = ((const float4*)(x + (size_t)row * D_MODEL))[t];
  float s  = v.x + v.y + v.z + v.w;
  float s2 = v.x*v.x + v.y*v.y + v.z*v.z + v.w*v.w;
#pragma unroll
  for (int o = 32; o > 0; o >>= 1) {
    s  += __shfl_down(s,  o, 64);
    s2 += __shfl_down(s2, o, 64);
  }
  __shared__ float ps[2], ps2[2];
  if ((t & 63) == 0) { ps[t >> 6] = s; ps2[t >> 6] = s2; }
  __syncthreads();
  s  = ps[0] + ps[1];
  s2 = ps2[0] + ps2[1];
  const float mu  = s * (1.0f / D_MODEL);
  const float var = s2 * (1.0f / D_MODEL) - mu * mu;
  const float rs  = rsqrtf(var + EPS);
  const float4 g = ((const float4*)gamma)[t];
  const float4 b = ((const float4*)beta)[t];
  ushort4 o;
  o.x = f2bf((v.x - mu) * rs * g.x + b.x);
  o.y = f2bf((v.y - mu) * rs * g.y + b.y);
  o.z = f2bf((v.z - mu) * rs * g.z + b.z);
  o.w = f2bf((v.w - mu) * rs * g.w + b.w);
  ((ushort4*)(xn + (size_t)row * D_MODEL))[t] = o;
}

// ---------------------------------------------------------------------------
// Shared bf16-MFMA GEMM tile: C[64x64] = A[64rows x 512] * W[512 x 64cols].
// Structure mirrors the attn QK^T/Vt patterns exactly:
//   A (bf16, row-major): preloaded to registers, frag = 8 contiguous k/lane.
//   W (fp32, row-major [K][N]): per 32-k tile, transposed into LDS
//   Wt[64 n][40] (pad like Vt keeps b128 reads 16B-aligned, ~2-way banks).
//   B-frag = Wt row (output col) x 8 contiguous k  -> gemm_bt operand form.
// Known flaw (accepted until counters say otherwise): Wt STORES are ~8-way
// bank-conflicted with this lane->role map.
// ---------------------------------------------------------------------------
__device__ __forceinline__ void bf16_gemm_tile(const unsigned short* __restrict__ A,
                                               const float* __restrict__ W,
                                               unsigned short (&Wt)[64 * 40],
                                               f32x4 (&acc)[4],
                                               int bm, int bn) {
  const int tid  = threadIdx.x;
  const int lane = tid & 63;
  const int l4   = lane & 15;
  const int lg   = lane >> 4;
  const int wv   = tid >> 6;

  // A-frags: lane holds A[row = bm*64 + wv*16 + l4][kt*32 + lg*8 + j]
  short8 af[16];
  const unsigned short* ap = A + (size_t)(bm * 64 + wv * 16 + l4) * D_MODEL + lg * 8;
#pragma unroll
  for (int kt = 0; kt < 16; kt++)
    af[kt] = *(const short8*)(ap + kt * 32);

  const int wk  = tid >> 3;        // k-row within tile 0..31
  const int wn0 = (tid & 7) * 8;   // local n octet

  for (int kt = 0; kt < 16; kt++) {
    const float* wp = W + (size_t)(kt * 32 + wk) * D_MODEL + bn * 64 + wn0;
    const float4 f0 = *(const float4*)wp;
    const float4 f1 = *(const float4*)(wp + 4);
    const float vals[8] = {f0.x, f0.y, f0.z, f0.w, f1.x, f1.y, f1.z, f1.w};
    __syncthreads();  // previous tile fully consumed
#pragma unroll
    for (int i = 0; i < 8; i++)
      Wt[(wn0 + i) * 40 + wk] = f2bf(vals[i]);
    __syncthreads();
#pragma unroll
    for (int nt = 0; nt < 4; nt++) {
      const short8 b = *(const short8*)&Wt[(nt * 16 + l4) * 40 + lg * 8];
      acc[nt] = __builtin_amdgcn_mfma_f32_16x16x32_bf16(af[kt], b, acc[nt], 0, 0, 0);
    }
  }
}

// ---------------------------------------------------------------------------
// Kernel 2: QKV projection, bf16 MFMA. grid = (ROWS/64, N_HEADS, 3).
// blockIdx.y == head (N-tile of 64 == D_HEAD). q output pre-scaled by 1/8
// (exact pow2; reference scales q AFTER bias, so (acc+bias)*scale).
// ---------------------------------------------------------------------------
__global__ __launch_bounds__(256) void qkv_mfma_kernel(const unsigned short* __restrict__ xn,
                                                       const float* __restrict__ wq, const float* __restrict__ bq,
                                                       const float* __restrict__ wk, const float* __restrict__ bk,
                                                       const float* __restrict__ wv, const float* __restrict__ bv,
                                                       unsigned short* __restrict__ qo,
                                                       unsigned short* __restrict__ ko,
                                                       unsigned short* __restrict__ vo) {
  __shared__ __align__(16) unsigned short Wt[64 * 40];
  const float* W; const float* bias; unsigned short* out; float scale;
  switch (blockIdx.z) {
    case 0:  W = wq; bias = bq; out = qo; scale = SCALE; break;
    case 1:  W = wk; bias = bk; out = ko; scale = 1.0f;  break;
    default: W = wv; bias = bv; out = vo; scale = 1.0f;  break;
  }
  f32x4 acc[4];
#pragma unroll
  for (int i = 0; i < 4; i++) acc[i] = (f32x4){0.f, 0.f, 0.f, 0.f};
  bf16_gemm_tile(xn, W, Wt, acc, blockIdx.x, blockIdx.y);

  const int lane = threadIdx.x & 63, wv_ = threadIdx.x >> 6;
  const int l4 = lane & 15, lg = lane >> 4;
  const int h = blockIdx.y;
#pragma unroll
  for (int nt = 0; nt < 4; nt++) {
    const float bb = bias[h * 64 + nt * 16 + l4];
#pragma unroll
    for (int r = 0; r < 4; r++) {
      const int row = blockIdx.x * 64 + wv_ * 16 + lg * 4 + r;
      const int b_  = row >> 11;          // row / SEQ
      const int s   = row & (SEQ - 1);    // row % SEQ
      out[((size_t)(b_ * N_HEADS + h) * SEQ + s) * D_HEAD + nt * 16 + l4] =
          f2bf((acc[nt][r] + bb) * scale);
    }
  }
}

// ---------------------------------------------------------------------------
// Kernel 3: MFMA flash attention (bf16 in/out, fp32 accumulate).
// Logic identical to the audited R3-R5 version; only I/O is now bf16
// (direct short8 copies, no converts in staging; q pre-scaled upstream).
// ---------------------------------------------------------------------------
__global__ __launch_bounds__(256) void attn_mfma_kernel(const unsigned short* __restrict__ q,
                                                        const unsigned short* __restrict__ k,
                                                        const unsigned short* __restrict__ v,
                                                        unsigned short* __restrict__ att) {
  // K: [32 rows][64 el] bf16, 16B-granule XOR swizzle (g ^= row&7) both sides.
  __shared__ __align__(16) unsigned short K_lds[32 * 64];
  // V^T: [64 d][40] (pad keeps b128 rows 16B-aligned, ~2-way banks)
  __shared__ __align__(16) unsigned short Vt_lds[64 * 40];
  // P per wave: [16 q][40]
  __shared__ __align__(16) unsigned short P_lds[4][16 * 40];

  const int tid  = threadIdx.x;
  const int lane = tid & 63;
  const int w    = tid >> 6;
  const int l4   = lane & 15;     // C/D col | A row | B col
  const int lg   = lane >> 4;     // lane group 0..3 (k-slice / C row block)

  // XCD-chunked swizzle: each XCD gets 4 complete heads -> K/V L2-resident.
  const int swz = (blockIdx.x & 7) * 128 + (blockIdx.x >> 3);
  const int qb  = swz & 31;       // q-block (64 rows)
  const int bh  = swz >> 5;       // batch*head

  const unsigned short* qbase = q + (size_t)bh * SEQ * D_HEAD;
  const unsigned short* kbase = k + (size_t)bh * SEQ * D_HEAD;
  const unsigned short* vbase = v + (size_t)bh * SEQ * D_HEAD;

  // Q A-frags: lane holds Q[row=l4][d = dt*32 + lg*8 + (0..7)]
  short8 aq[2];
  {
    const unsigned short* qp = qbase + (size_t)(qb * 64 + w * 16 + l4) * D_HEAD + lg * 8;
    aq[0] = *(const short8*)(qp);
    aq[1] = *(const short8*)(qp + 32);
  }

  f32x4 o[4];
#pragma unroll
  for (int i = 0; i < 4; i++) o[i] = (f32x4){0.f, 0.f, 0.f, 0.f};
  float m_[4] = {-1e30f, -1e30f, -1e30f, -1e30f};
  float l_[4] = {0.f, 0.f, 0.f, 0.f};

  // staging roles (256 threads, 16B per thread per buffer)
  const int kj   = tid >> 3;                 // K row 0..31
  const int kg   = tid & 7;                  // 16B granule 0..7
  const int kswz = kg ^ (kj & 7);            // swizzled granule
  const int vj   = tid & 31;                 // V row (j)
  const int vd0  = (tid >> 5) * 8;           // V d-offset 0..56

  for (int t = 0; t < SEQ / 32; t++) {
    const int kv0 = t * 32;
    {  // stage K tile: one short8 copy per thread
      const short8 pk = *(const short8*)(kbase + (size_t)(kv0 + kj) * D_HEAD + kg * 8);
      *(short8*)&K_lds[kj * 64 + kswz * 8] = pk;
    }
    {  // stage V^T tile: short8 load, 8 scalar transposed writes
      const short8 vv = *(const short8*)(vbase + (size_t)(kv0 + vj) * D_HEAD + vd0);
#pragma unroll
      for (int i = 0; i < 8; i++)
        Vt_lds[(vd0 + i) * 40 + vj] = (unsigned short)vv[i];
    }
    __syncthreads();

    // QK^T: two 16(q) x 16(k) score tiles, contraction d=64 (2 mfma each)
    f32x4 s[2];
#pragma unroll
    for (int kt2 = 0; kt2 < 2; kt2++) {
      const int krow = kt2 * 16 + l4;
      f32x4 acc = (f32x4){0.f, 0.f, 0.f, 0.f};
#pragma unroll
      for (int dt = 0; dt < 2; dt++) {
        const int g = (lg + dt * 4) ^ (krow & 7);
        const short8 bk = *(const short8*)&K_lds[krow * 64 + g * 8];
        acc = __builtin_amdgcn_mfma_f32_16x16x32_bf16(aq[dt], bk, acc, 0, 0, 0);
      }
      s[kt2] = acc;
    }

    // online softmax. Lane holds rows q=lg*4+r (r=0..3), col j=kt2*16+l4.
#pragma unroll
    for (int r = 0; r < 4; r++) {
      float mt = fmaxf(s[0][r], s[1][r]);
#pragma unroll
      for (int mask = 1; mask <= 8; mask <<= 1)
        mt = fmaxf(mt, __shfl_xor(mt, mask, 64));
      const float mn   = fmaxf(m_[r], mt);
      const float corr = __expf(m_[r] - mn);
      const float p0 = __expf(s[0][r] - mn);
      const float p1 = __expf(s[1][r] - mn);
      float rs = p0 + p1;
#pragma unroll
      for (int mask = 1; mask <= 8; mask <<= 1)
        rs += __shfl_xor(rs, mask, 64);
      l_[r] = l_[r] * corr + rs;
      m_[r] = mn;
      o[0][r] *= corr; o[1][r] *= corr; o[2][r] *= corr; o[3][r] *= corr;
      const int qr = lg * 4 + r;
      P_lds[w][qr * 40 + l4]      = f2bf(p0);
      P_lds[w][qr * 40 + 16 + l4] = f2bf(p1);
    }
    // same-wave LDS write->read: lockstep wave + drained lgkm is sufficient
    asm volatile("s_waitcnt lgkmcnt(0)" ::: "memory");
    __builtin_amdgcn_sched_barrier(0);

    // PV: O[q][d] += P(16x32) * V(32x64), one mfma per 16-d tile
    const short8 pa = *(const short8*)&P_lds[w][l4 * 40 + lg * 8];
#pragma unroll
    for (int dtile = 0; dtile < 4; dtile++) {
      const short8 bv = *(const short8*)&Vt_lds[(dtile * 16 + l4) * 40 + lg * 8];
      o[dtile] = __builtin_amdgcn_mfma_f32_16x16x32_bf16(pa, bv, o[dtile], 0, 0, 0);
    }
    __syncthreads();  // all waves done reading K/Vt before next staging
  }

  // epilogue: divide by l, write bf16 att[b][s][h*64+d]
  const int b_ = bh >> 3, h = bh & 7;
#pragma unroll
  for (int r = 0; r < 4; r++) {
    const int qrow = qb * 64 + w * 16 + lg * 4 + r;
    const float inv = 1.0f / l_[r];
    unsigned short* op = att + ((size_t)(b_ * SEQ + qrow)) * D_MODEL + h * D_HEAD;
#pragma unroll
    for (int dtile = 0; dtile < 4; dtile++)
      op[dtile * 16 + l4] = f2bf(o[dtile][r] * inv);
  }
}

// ---------------------------------------------------------------------------
// Kernel 4: output projection, bf16 MFMA + fp32 bias + residual.
// grid = (ROWS/64, 8).
// ---------------------------------------------------------------------------
__global__ __launch_bounds__(256) void proj_mfma_kernel(const unsigned short* __restrict__ att,
                                                        const float* __restrict__ wo,
                                                        const float* __restrict__ bo,
                                                        const float* __restrict__ x,
                                                        float* __restrict__ out) {
  __shared__ __align__(16) unsigned short Wt[64 * 40];
  f32x4 acc[4];
#pragma unroll
  for (int i = 0; i < 4; i++) acc[i] = (f32x4){0.f, 0.f, 0.f, 0.f};
  bf16_gemm_tile(att, wo, Wt, acc, blockIdx.x, blockIdx.y);

  const int lane = threadIdx.x & 63, wv_ = threadIdx.x >> 6;
  const int l4 = lane & 15, lg = lane >> 4;
#pragma unroll
  for (int nt = 0; nt < 4; nt++) {
    const float bb = bo[blockIdx.y * 64 + nt * 16 + l4];
#pragma unroll
    for (int r = 0; r < 4; r++) {
      const int row = blockIdx.x * 64 + wv_ * 16 + lg * 4 + r;
      const size_t off = (size_t)row * D_MODEL + blockIdx.y * 64 + nt * 16 + l4;
      out[off] = acc[nt][r] + bb + x[off];
    }
  }
}

// ---------------------------------------------------------------------------
extern "C" void kernel_launch(void* const* d_in, const int* in_sizes, int n_in,
                              void* d_out, int out_size, void* d_ws, size_t ws_size,
                              hipStream_t stream) {
  const float* x     = (const float*)d_in[0];
  const float* wq    = (const float*)d_in[1];
  const float* bq    = (const float*)d_in[2];
  const float* wk    = (const float*)d_in[3];
  const float* bk    = (const float*)d_in[4];
  const float* wv    = (const float*)d_in[5];
  const float* bv    = (const float*)d_in[6];
  const float* wo    = (const float*)d_in[7];
  const float* bo    = (const float*)d_in[8];
  const float* gamma = (const float*)d_in[9];
  const float* beta  = (const float*)d_in[10];
  float* out = (float*)d_out;

  // bf16 workspace: xn | q | k | v  (4 x 8 MiB); att reuses xn's slot
  unsigned short* xn  = (unsigned short*)d_ws;
  unsigned short* q   = xn + (size_t)ROWS * D_MODEL;
  unsigned short* k   = q  + (size_t)ROWS * D_MODEL;
  unsigned short* v   = k  + (size_t)ROWS * D_MODEL;
  unsigned short* att = xn;  // xn dead after qkv

  ln_kernel<<<ROWS, 128, 0, stream>>>(x, gamma, beta, xn);
  qkv_mfma_kernel<<<dim3(ROWS / 64, N_HEADS, 3), 256, 0, stream>>>(
      xn, wq, bq, wk, bk, wv, bv, q, k, v);
  attn_mfma_kernel<<<1024, 256, 0, stream>>>(q, k, v, att);
  proj_mfma_kernel<<<dim3(ROWS / 64, D_MODEL / 64), 256, 0, stream>>>(att, wo, bo, x, out);
}